// Round 2
// baseline (484.586 us; speedup 1.0000x reference)
//
#include <hip/hip_runtime.h>
#include <hip/hip_bf16.h>

using short8  = __attribute__((ext_vector_type(8))) short;
using ushort8 = __attribute__((ext_vector_type(8))) unsigned short;
using floatx4 = __attribute__((ext_vector_type(4))) float;

#define EPSV 1e-4f

__device__ __forceinline__ unsigned short bfbits(float f) {
  __hip_bfloat16 h = __float2bfloat16(f);
  return *reinterpret_cast<unsigned short*>(&h);
}

// ---------------- convert 5 weight matrices f32 -> bf16 (contiguous dst) ----------------
// sizes/4: Wf 98304, W1 32768, W2 16384, W3 8192, W4 4096  (total 159744 float4s)
__global__ void cvt_weights(const float4* __restrict__ Wf, const float4* __restrict__ W1,
                            const float4* __restrict__ W2, const float4* __restrict__ W3,
                            const float4* __restrict__ W4, ushort4* __restrict__ dst) {
  int t = blockIdx.x * 256 + threadIdx.x;   // 159744 exact
  const float4* src; int off;
  if (t < 98304)       { src = Wf; off = 0; }
  else if (t < 131072) { src = W1; off = 98304; }
  else if (t < 147456) { src = W2; off = 131072; }
  else if (t < 155648) { src = W3; off = 147456; }
  else                 { src = W4; off = 155648; }
  float4 v = src[t - off];
  ushort4 o;
  o.x = bfbits(v.x); o.y = bfbits(v.y); o.z = bfbits(v.z); o.w = bfbits(v.w);
  dst[t] = o;
}

// ---------------- im2col: x(16,3,224,224) f32 -> A0[3136,768] bf16 ----------------
// row = b*196 + i*14 + j ; col = c*256 + kh*16 + kw
__global__ void im2col_kernel(const float* __restrict__ x,
                              __hip_bfloat16* __restrict__ A0) {
  int t = blockIdx.x * 256 + threadIdx.x;   // 150528 = 3136*3*16 exact
  int kh = t & 15;
  int rest = t >> 4;
  int c = rest % 3;
  int row = rest / 3;          // 0..3135
  int b = row / 196;
  int ij = row - b * 196;
  int i = ij / 14;
  int j = ij - i * 14;
  const float4* s4 = reinterpret_cast<const float4*>(
      x + ((size_t)(b * 3 + c) * 224 + (size_t)(i * 16 + kh)) * 224 + j * 16);
  __hip_bfloat16* dst = A0 + (size_t)row * 768 + c * 256 + kh * 16;
  float4 v0 = s4[0], v1 = s4[1], v2 = s4[2], v3 = s4[3];
  ushort8 o0, o1;
  o0[0] = bfbits(v0.x); o0[1] = bfbits(v0.y); o0[2] = bfbits(v0.z); o0[3] = bfbits(v0.w);
  o0[4] = bfbits(v1.x); o0[5] = bfbits(v1.y); o0[6] = bfbits(v1.z); o0[7] = bfbits(v1.w);
  o1[0] = bfbits(v2.x); o1[1] = bfbits(v2.y); o1[2] = bfbits(v2.z); o1[3] = bfbits(v2.w);
  o1[4] = bfbits(v3.x); o1[5] = bfbits(v3.y); o1[6] = bfbits(v3.z); o1[7] = bfbits(v3.w);
  ushort8* d8 = reinterpret_cast<ushort8*>(dst);
  d8[0] = o0;
  d8[1] = o1;
}

// ---------------- GEMM: C[M,N] = act(A[M,K] * W[N,K]^T + bias[N]) ----------------
// One wave per 64x64 tile. MFMA 16x16x32 bf16.
// A-frag: m = lane&15, k = (lane>>4)*8 + j. B-frag: n = lane&15, same k.
// C/D: col = lane&15, row = (lane>>4)*4 + reg.
template <int ACT>   // 0 = relu, 1 = sigmoid
__global__ void gemm_bt(const __hip_bfloat16* __restrict__ A,
                        const __hip_bfloat16* __restrict__ W,
                        const float* __restrict__ bias,
                        __hip_bfloat16* __restrict__ C,
                        int M, int N, int K) {
  const int m0 = blockIdx.x * 64;
  const int n0 = blockIdx.y * 64;
  const int lane = threadIdx.x;      // 0..63
  const int r = lane & 15;
  const int q = lane >> 4;

  const __hip_bfloat16* Abase = A + (size_t)(m0 + r) * K + q * 8;
  const __hip_bfloat16* Wbase = W + (size_t)(n0 + r) * K + q * 8;

  floatx4 acc[4][4] = {};
  for (int k = 0; k < K; k += 32) {
    short8 a[4], b[4];
#pragma unroll
    for (int i = 0; i < 4; ++i) {
      a[i] = *reinterpret_cast<const short8*>(Abase + (size_t)i * 16 * K + k);
      b[i] = *reinterpret_cast<const short8*>(Wbase + (size_t)i * 16 * K + k);
    }
#pragma unroll
    for (int mi = 0; mi < 4; ++mi)
#pragma unroll
      for (int ni = 0; ni < 4; ++ni)
        acc[mi][ni] = __builtin_amdgcn_mfma_f32_16x16x32_bf16(a[mi], b[ni], acc[mi][ni], 0, 0, 0);
  }

#pragma unroll
  for (int mi = 0; mi < 4; ++mi) {
#pragma unroll
    for (int ni = 0; ni < 4; ++ni) {
      int col = n0 + ni * 16 + r;
      float bv = bias[col];
#pragma unroll
      for (int rr = 0; rr < 4; ++rr) {
        int row = m0 + mi * 16 + q * 4 + rr;
        float v = acc[mi][ni][rr] + bv;
        if (ACT == 0) v = fmaxf(v, 0.0f);
        else          v = 1.0f / (1.0f + __expf(-v));
        C[(size_t)row * N + col] = __float2bfloat16(v);
      }
    }
  }
}

// ---------------- distances + act: h4[3136,128] bf16, proto[60,128] f32 ----------------
// dist/act layout: [b][p][hw], hw = i*14+j, pos_global = b*196+hw
__global__ void dist_act_kernel(const __hip_bfloat16* __restrict__ h4,
                                const float* __restrict__ proto,
                                float* __restrict__ dist,
                                float* __restrict__ act) {
  __shared__ float hs[64][129];   // stride 129: conflict-free for lane==pos
  __shared__ float ps[60][128];
  const int t = threadIdx.x;      // 256 threads
  const int pos0 = blockIdx.x * 64;

  for (int i = t; i < 64 * 128; i += 256) {
    int pp = i >> 7, kk = i & 127;
    hs[pp][kk] = __bfloat162float(h4[(size_t)(pos0 + pp) * 128 + kk]);
  }
  for (int i = t; i < 60 * 128; i += 256)
    ps[i >> 7][i & 127] = proto[i];
  __syncthreads();

  for (int qq = t; qq < 64 * 60; qq += 256) {
    int p = qq >> 6;
    int pos = qq & 63;
    float s = 0.0f;
#pragma unroll 8
    for (int k = 0; k < 128; ++k) {
      float dv = hs[pos][k] - ps[p][k];
      s = fmaf(dv, dv, s);
    }
    float d = sqrtf(s);
    float a = __logf((d + 1.0f) / (d + EPSV));
    int gpos = pos0 + pos;
    int bimg = gpos / 196;
    int hw = gpos - bimg * 196;
    size_t idx = ((size_t)bimg * 60 + p) * 196 + hw;
    dist[idx] = d;
    act[idx] = a;
  }
}

// ---------------- top-5 smallest distances per (b,p) ----------------
// act = log((d+1)/(d+eps)) is strictly decreasing in d, so top-5 act == act of
// the 5 smallest distances. One thread per (b,p) unit (960 total).
__global__ void topk_kernel(const float* __restrict__ dist,
                            float* __restrict__ proto_act,
                            float* __restrict__ out_mind) {
  int u = blockIdx.x * 256 + threadIdx.x;
  if (u >= 960) return;
  const float* rowp = dist + (size_t)u * 196;
  float best[5] = {1e30f, 1e30f, 1e30f, 1e30f, 1e30f};
  for (int i = 0; i < 196; ++i) {
    float d = rowp[i];
    if (d < best[4]) {
      int j = 4;
      while (j > 0 && best[j - 1] > d) { best[j] = best[j - 1]; --j; }
      best[j] = d;
    }
  }
  float sd = 0.0f, sa = 0.0f;
#pragma unroll
  for (int j = 0; j < 5; ++j) {
    sd += best[j];
    sa += __logf((best[j] + 1.0f) / (best[j] + EPSV));
  }
  out_mind[u] = sd * 0.2f;
  proto_act[u] = sa * 0.2f;
}

// ---------------- logits[16,3] = proto_act[16,60] @ last_W[3,60]^T ----------------
__global__ void logits_kernel(const float* __restrict__ proto_act,
                              const float* __restrict__ lastW,
                              float* __restrict__ out) {
  int t = threadIdx.x;
  if (t < 48) {
    int b = t / 3, c = t - b * 3;
    float s = 0.0f;
    for (int p = 0; p < 60; ++p)
      s += proto_act[b * 60 + p] * lastW[c * 60 + p];
    out[t] = s;
  }
}

// ---------------- upsample 16x: act[16,60,14,14] f32 -> out[16,60,224,224] f32 ----------------
// One thread writes one 16-element run (one source value) = 64 B.
__global__ void upsample_kernel(const float* __restrict__ act,
                                float* __restrict__ up) {
  int g = blockIdx.x * 256 + threadIdx.x;   // 3,014,400 exact
  int j = g % 14;
  int rem = g / 14;
  int y = rem % 224;
  int bp = rem / 224;
  float v = act[(size_t)bp * 196 + (y >> 4) * 14 + j];
  float4 val;
  val.x = v; val.y = v; val.z = v; val.w = v;
  float4* dst = reinterpret_cast<float4*>(up + (size_t)g * 16);
  dst[0] = val;
  dst[1] = val;
  dst[2] = val;
  dst[3] = val;
}

extern "C" void kernel_launch(void* const* d_in, const int* in_sizes, int n_in,
                              void* d_out, int out_size, void* d_ws, size_t ws_size,
                              hipStream_t stream) {
  const float* x     = (const float*)d_in[0];
  // d_in[1] = mascaras (unused by the reference forward)
  const float* Wf    = (const float*)d_in[2];   // [512,768]
  const float* bf    = (const float*)d_in[3];
  const float* W1    = (const float*)d_in[4];   // [256,512]
  const float* b1    = (const float*)d_in[5];
  const float* W2    = (const float*)d_in[6];   // [256,256]
  const float* b2    = (const float*)d_in[7];
  const float* W3    = (const float*)d_in[8];   // [128,256]
  const float* b3    = (const float*)d_in[9];
  const float* W4    = (const float*)d_in[10];  // [128,128]
  const float* b4    = (const float*)d_in[11];
  const float* proto = (const float*)d_in[12];  // [60,128]
  const float* lastW = (const float*)d_in[13];  // [3,60]
  // d_in[14] = topk_k == 5 (fixed by setup_inputs)

  char* ws = (char*)d_ws;
  // bf16 weights (contiguous, written by cvt_weights):
  __hip_bfloat16* WfB = (__hip_bfloat16*)(ws + 0);         // 393216 elems
  __hip_bfloat16* W1B = (__hip_bfloat16*)(ws + 786432);    // 131072
  __hip_bfloat16* W2B = (__hip_bfloat16*)(ws + 1048576);   // 65536
  __hip_bfloat16* W3B = (__hip_bfloat16*)(ws + 1179648);   // 32768
  __hip_bfloat16* W4B = (__hip_bfloat16*)(ws + 1245184);   // 16384 (ends 1,277,952)
  // activations:
  __hip_bfloat16* A0 = (__hip_bfloat16*)(ws + 1310720);    // [3136,768] -> ends 6,128,128
  __hip_bfloat16* h1 = (__hip_bfloat16*)(ws + 1310720);    // [3136,256] (A0 dead after L0)
  __hip_bfloat16* h2 = (__hip_bfloat16*)(ws + 2916352);    // [3136,256]
  __hip_bfloat16* h3 = (__hip_bfloat16*)(ws + 4521984);    // [3136,128]
  __hip_bfloat16* f  = (__hip_bfloat16*)(ws + 6128128);    // [3136,512] -> ends 9,339,392
  __hip_bfloat16* h4 = (__hip_bfloat16*)(ws + 6128128);    // [3136,128] (f dead after L1)
  float* dist = (float*)(ws + 6930944);                    // [960,196] f32
  float* act  = (float*)(ws + 7683584);                    // [960,196] f32
  float* pact = (float*)(ws + 8436224);                    // [960] f32

  float* out        = (float*)d_out;
  float* out_logits = out;          // 48
  float* out_mind   = out + 48;     // 960
  float* out_up     = out + 1008;   // 48,230,400

  cvt_weights<<<624, 256, 0, stream>>>((const float4*)Wf, (const float4*)W1,
                                       (const float4*)W2, (const float4*)W3,
                                       (const float4*)W4, (ushort4*)WfB);
  im2col_kernel<<<588, 256, 0, stream>>>(x, A0);
  gemm_bt<0><<<dim3(49, 8), 64, 0, stream>>>(A0, WfB, bf, f,  3136, 512, 768);
  gemm_bt<0><<<dim3(49, 4), 64, 0, stream>>>(f,  W1B, b1, h1, 3136, 256, 512);
  gemm_bt<0><<<dim3(49, 4), 64, 0, stream>>>(h1, W2B, b2, h2, 3136, 256, 256);
  gemm_bt<0><<<dim3(49, 2), 64, 0, stream>>>(h2, W3B, b3, h3, 3136, 128, 256);
  gemm_bt<1><<<dim3(49, 2), 64, 0, stream>>>(h3, W4B, b4, h4, 3136, 128, 128);
  dist_act_kernel<<<49, 256, 0, stream>>>(h4, proto, dist, act);
  topk_kernel<<<4, 256, 0, stream>>>(dist, pact, out_mind);
  logits_kernel<<<1, 64, 0, stream>>>(pact, lastW, out_logits);
  upsample_kernel<<<11775, 256, 0, stream>>>(act, out_up);
}

// Round 3
// 334.820 us; speedup vs baseline: 1.4473x; 1.4473x over previous
//
#include <hip/hip_runtime.h>
#include <hip/hip_bf16.h>

using short8  = __attribute__((ext_vector_type(8))) short;
using ushort8 = __attribute__((ext_vector_type(8))) unsigned short;
using floatx4 = __attribute__((ext_vector_type(4))) float;

#define EPSV 1e-4f

__device__ __forceinline__ unsigned short bfbits(float f) {
  __hip_bfloat16 h = __float2bfloat16(f);
  return *reinterpret_cast<unsigned short*>(&h);
}

// ---------------- convert 5 weight matrices f32 -> bf16 (contiguous dst) ----------------
__global__ void cvt_weights(const float4* __restrict__ Wf, const float4* __restrict__ W1,
                            const float4* __restrict__ W2, const float4* __restrict__ W3,
                            const float4* __restrict__ W4, ushort4* __restrict__ dst) {
  int t = blockIdx.x * 256 + threadIdx.x;   // 159744 exact
  const float4* src; int off;
  if (t < 98304)       { src = Wf; off = 0; }
  else if (t < 131072) { src = W1; off = 98304; }
  else if (t < 147456) { src = W2; off = 131072; }
  else if (t < 155648) { src = W3; off = 147456; }
  else                 { src = W4; off = 155648; }
  float4 v = src[t - off];
  ushort4 o;
  o.x = bfbits(v.x); o.y = bfbits(v.y); o.z = bfbits(v.z); o.w = bfbits(v.w);
  dst[t] = o;
}

// ---------------- im2col: x(16,3,224,224) f32 -> A0[3136,768] bf16 ----------------
__global__ void im2col_kernel(const float* __restrict__ x,
                              __hip_bfloat16* __restrict__ A0) {
  int t = blockIdx.x * 256 + threadIdx.x;   // 150528 = 3136*3*16 exact
  int kh = t & 15;
  int rest = t >> 4;
  int c = rest % 3;
  int row = rest / 3;          // 0..3135
  int b = row / 196;
  int ij = row - b * 196;
  int i = ij / 14;
  int j = ij - i * 14;
  const float4* s4 = reinterpret_cast<const float4*>(
      x + ((size_t)(b * 3 + c) * 224 + (size_t)(i * 16 + kh)) * 224 + j * 16);
  __hip_bfloat16* dst = A0 + (size_t)row * 768 + c * 256 + kh * 16;
  float4 v0 = s4[0], v1 = s4[1], v2 = s4[2], v3 = s4[3];
  ushort8 o0, o1;
  o0[0] = bfbits(v0.x); o0[1] = bfbits(v0.y); o0[2] = bfbits(v0.z); o0[3] = bfbits(v0.w);
  o0[4] = bfbits(v1.x); o0[5] = bfbits(v1.y); o0[6] = bfbits(v1.z); o0[7] = bfbits(v1.w);
  o1[0] = bfbits(v2.x); o1[1] = bfbits(v2.y); o1[2] = bfbits(v2.z); o1[3] = bfbits(v2.w);
  o1[4] = bfbits(v3.x); o1[5] = bfbits(v3.y); o1[6] = bfbits(v3.z); o1[7] = bfbits(v3.w);
  ushort8* d8 = reinterpret_cast<ushort8*>(dst);
  d8[0] = o0;
  d8[1] = o1;
}

// ---------------- GEMM: C[M,N] = act(A[M,K] * W[N,K]^T + bias[N]) ----------------
// One wave per 64x64 tile. MFMA 16x16x32 bf16.
template <int ACT>   // 0 = relu, 1 = sigmoid
__global__ void gemm_bt(const __hip_bfloat16* __restrict__ A,
                        const __hip_bfloat16* __restrict__ W,
                        const float* __restrict__ bias,
                        __hip_bfloat16* __restrict__ C,
                        int M, int N, int K) {
  const int m0 = blockIdx.x * 64;
  const int n0 = blockIdx.y * 64;
  const int lane = threadIdx.x;      // 0..63
  const int r = lane & 15;
  const int q = lane >> 4;

  const __hip_bfloat16* Abase = A + (size_t)(m0 + r) * K + q * 8;
  const __hip_bfloat16* Wbase = W + (size_t)(n0 + r) * K + q * 8;

  floatx4 acc[4][4] = {};
  for (int k = 0; k < K; k += 32) {
    short8 a[4], b[4];
#pragma unroll
    for (int i = 0; i < 4; ++i) {
      a[i] = *reinterpret_cast<const short8*>(Abase + (size_t)i * 16 * K + k);
      b[i] = *reinterpret_cast<const short8*>(Wbase + (size_t)i * 16 * K + k);
    }
#pragma unroll
    for (int mi = 0; mi < 4; ++mi)
#pragma unroll
      for (int ni = 0; ni < 4; ++ni)
        acc[mi][ni] = __builtin_amdgcn_mfma_f32_16x16x32_bf16(a[mi], b[ni], acc[mi][ni], 0, 0, 0);
  }

#pragma unroll
  for (int mi = 0; mi < 4; ++mi) {
#pragma unroll
    for (int ni = 0; ni < 4; ++ni) {
      int col = n0 + ni * 16 + r;
      float bv = bias[col];
#pragma unroll
      for (int rr = 0; rr < 4; ++rr) {
        int row = m0 + mi * 16 + q * 4 + rr;
        float v = acc[mi][ni][rr] + bv;
        if (ACT == 0) v = fmaxf(v, 0.0f);
        else          v = 1.0f / (1.0f + __expf(-v));
        C[(size_t)row * N + col] = __float2bfloat16(v);
      }
    }
  }
}

// ---------------- distances + act ----------------
__global__ void dist_act_kernel(const __hip_bfloat16* __restrict__ h4,
                                const float* __restrict__ proto,
                                float* __restrict__ dist,
                                float* __restrict__ act) {
  __shared__ float hs[64][129];
  __shared__ float ps[60][128];
  const int t = threadIdx.x;      // 256 threads
  const int pos0 = blockIdx.x * 64;

  for (int i = t; i < 64 * 128; i += 256) {
    int pp = i >> 7, kk = i & 127;
    hs[pp][kk] = __bfloat162float(h4[(size_t)(pos0 + pp) * 128 + kk]);
  }
  for (int i = t; i < 60 * 128; i += 256)
    ps[i >> 7][i & 127] = proto[i];
  __syncthreads();

  for (int qq = t; qq < 64 * 60; qq += 256) {
    int p = qq >> 6;
    int pos = qq & 63;
    float s = 0.0f;
#pragma unroll 8
    for (int k = 0; k < 128; ++k) {
      float dv = hs[pos][k] - ps[p][k];
      s = fmaf(dv, dv, s);
    }
    float d = sqrtf(s);
    float a = __logf((d + 1.0f) / (d + EPSV));
    int gpos = pos0 + pos;
    int bimg = gpos / 196;
    int hw = gpos - bimg * 196;
    size_t idx = ((size_t)bimg * 60 + p) * 196 + hw;
    dist[idx] = d;
    act[idx] = a;
  }
}

// ---------------- top-5 smallest distances per (b,p): one WAVE per unit ----------------
// act = log((d+1)/(d+eps)) is strictly decreasing in d, so top-5 act == act of
// the 5 smallest distances. 960 units -> 240 blocks x 4 waves.
__global__ void topk_kernel(const float* __restrict__ dist,
                            float* __restrict__ proto_act,
                            float* __restrict__ out_mind) {
  const int wid = threadIdx.x >> 6;
  const int lane = threadIdx.x & 63;
  const int u = blockIdx.x * 4 + wid;          // 0..959 exact (240 blocks)
  const float* rowp = dist + (size_t)u * 196;

  float v[4];
#pragma unroll
  for (int i = 0; i < 4; ++i) {
    int idx = lane + 64 * i;
    v[i] = (idx < 196) ? rowp[idx] : 1e30f;
  }

  float sd = 0.0f, sa = 0.0f;
#pragma unroll
  for (int round = 0; round < 5; ++round) {
    float lmin = fminf(fminf(v[0], v[1]), fminf(v[2], v[3]));
    float m = lmin;
#pragma unroll
    for (int off = 32; off >= 1; off >>= 1)
      m = fminf(m, __shfl_xor(m, off));
    unsigned long long msk = __ballot(lmin == m);
    int leader = __ffsll((long long)msk) - 1;
    if (lane == leader) {
      // retire one instance of m
      if (v[0] == m)      v[0] = 1e30f;
      else if (v[1] == m) v[1] = 1e30f;
      else if (v[2] == m) v[2] = 1e30f;
      else                v[3] = 1e30f;
    }
    sd += m;
    sa += __logf((m + 1.0f) / (m + EPSV));
  }
  if (lane == 0) {
    out_mind[u] = sd * 0.2f;
    proto_act[u] = sa * 0.2f;
  }
}

// ---------------- logits[16,3] = proto_act[16,60] @ last_W[3,60]^T ----------------
__global__ void logits_kernel(const float* __restrict__ proto_act,
                              const float* __restrict__ lastW,
                              float* __restrict__ out) {
  int t = threadIdx.x;
  if (t < 48) {
    int b = t / 3, c = t - b * 3;
    float s = 0.0f;
    for (int p = 0; p < 60; ++p)
      s += proto_act[b * 60 + p] * lastW[c * 60 + p];
    out[t] = s;
  }
}

// ---------------- upsample 16x: act[16,60,14,14] f32 -> out[16,60,224,224] f32 ----------------
// Thread t writes float4 at flat offset 4t -> each wave store = 1 KiB contiguous.
// Flat index decomposition: row of 224 = 56 float4s; col4 in [0,56): src j = col4>>2.
__global__ void upsample_kernel(const float* __restrict__ act,
                                float* __restrict__ up) {
  int t = blockIdx.x * 256 + threadIdx.x;   // 12,057,600 exact (47100 blocks)
  int col4 = t % 56;
  int rem = t / 56;
  int y = rem % 224;
  int bp = rem / 224;
  float v = act[(size_t)bp * 196 + (y >> 4) * 14 + (col4 >> 2)];
  float4 val;
  val.x = v; val.y = v; val.z = v; val.w = v;
  reinterpret_cast<float4*>(up)[t] = val;
}

extern "C" void kernel_launch(void* const* d_in, const int* in_sizes, int n_in,
                              void* d_out, int out_size, void* d_ws, size_t ws_size,
                              hipStream_t stream) {
  const float* x     = (const float*)d_in[0];
  const float* Wf    = (const float*)d_in[2];   // [512,768]
  const float* bf    = (const float*)d_in[3];
  const float* W1    = (const float*)d_in[4];   // [256,512]
  const float* b1    = (const float*)d_in[5];
  const float* W2    = (const float*)d_in[6];   // [256,256]
  const float* b2    = (const float*)d_in[7];
  const float* W3    = (const float*)d_in[8];   // [128,256]
  const float* b3    = (const float*)d_in[9];
  const float* W4    = (const float*)d_in[10];  // [128,128]
  const float* b4    = (const float*)d_in[11];
  const float* proto = (const float*)d_in[12];  // [60,128]
  const float* lastW = (const float*)d_in[13];  // [3,60]

  char* ws = (char*)d_ws;
  __hip_bfloat16* WfB = (__hip_bfloat16*)(ws + 0);         // 393216 elems
  __hip_bfloat16* W1B = (__hip_bfloat16*)(ws + 786432);    // 131072
  __hip_bfloat16* W2B = (__hip_bfloat16*)(ws + 1048576);   // 65536
  __hip_bfloat16* W3B = (__hip_bfloat16*)(ws + 1179648);   // 32768
  __hip_bfloat16* W4B = (__hip_bfloat16*)(ws + 1245184);   // 16384
  __hip_bfloat16* A0 = (__hip_bfloat16*)(ws + 1310720);    // [3136,768]
  __hip_bfloat16* h1 = (__hip_bfloat16*)(ws + 1310720);    // [3136,256] (A0 dead after L0)
  __hip_bfloat16* h2 = (__hip_bfloat16*)(ws + 2916352);    // [3136,256]
  __hip_bfloat16* h3 = (__hip_bfloat16*)(ws + 4521984);    // [3136,128]
  __hip_bfloat16* f  = (__hip_bfloat16*)(ws + 6128128);    // [3136,512]
  __hip_bfloat16* h4 = (__hip_bfloat16*)(ws + 6128128);    // [3136,128] (f dead after L1)
  float* dist = (float*)(ws + 6930944);                    // [960,196] f32
  float* act  = (float*)(ws + 7683584);                    // [960,196] f32
  float* pact = (float*)(ws + 8436224);                    // [960] f32

  float* out        = (float*)d_out;
  float* out_logits = out;          // 48
  float* out_mind   = out + 48;     // 960
  float* out_up     = out + 1008;   // 48,230,400

  cvt_weights<<<624, 256, 0, stream>>>((const float4*)Wf, (const float4*)W1,
                                       (const float4*)W2, (const float4*)W3,
                                       (const float4*)W4, (ushort4*)WfB);
  im2col_kernel<<<588, 256, 0, stream>>>(x, A0);
  gemm_bt<0><<<dim3(49, 8), 64, 0, stream>>>(A0, WfB, bf, f,  3136, 512, 768);
  gemm_bt<0><<<dim3(49, 4), 64, 0, stream>>>(f,  W1B, b1, h1, 3136, 256, 512);
  gemm_bt<0><<<dim3(49, 4), 64, 0, stream>>>(h1, W2B, b2, h2, 3136, 256, 256);
  gemm_bt<0><<<dim3(49, 2), 64, 0, stream>>>(h2, W3B, b3, h3, 3136, 128, 256);
  gemm_bt<1><<<dim3(49, 2), 64, 0, stream>>>(h3, W4B, b4, h4, 3136, 128, 128);
  dist_act_kernel<<<49, 256, 0, stream>>>(h4, proto, dist, act);
  topk_kernel<<<240, 256, 0, stream>>>(dist, pact, out_mind);
  logits_kernel<<<1, 64, 0, stream>>>(pact, lastW, out_logits);
  upsample_kernel<<<47100, 256, 0, stream>>>(act, out_up);
}

// Round 4
// 286.023 us; speedup vs baseline: 1.6942x; 1.1706x over previous
//
#include <hip/hip_runtime.h>
#include <hip/hip_bf16.h>

using short8  = __attribute__((ext_vector_type(8))) short;
using ushort8 = __attribute__((ext_vector_type(8))) unsigned short;
using floatx4 = __attribute__((ext_vector_type(4))) float;

#define EPSV 1e-4f

__device__ __forceinline__ unsigned short bfbits(float f) {
  __hip_bfloat16 h = __float2bfloat16(f);
  return *reinterpret_cast<unsigned short*>(&h);
}

// ---------------- convert 5 weight matrices f32 -> bf16 (contiguous dst) ----------------
__global__ void cvt_weights(const float4* __restrict__ Wf, const float4* __restrict__ W1,
                            const float4* __restrict__ W2, const float4* __restrict__ W3,
                            const float4* __restrict__ W4, ushort4* __restrict__ dst) {
  int t = blockIdx.x * 256 + threadIdx.x;   // 159744 exact
  const float4* src; int off;
  if (t < 98304)       { src = Wf; off = 0; }
  else if (t < 131072) { src = W1; off = 98304; }
  else if (t < 147456) { src = W2; off = 131072; }
  else if (t < 155648) { src = W3; off = 147456; }
  else                 { src = W4; off = 155648; }
  float4 v = src[t - off];
  ushort4 o;
  o.x = bfbits(v.x); o.y = bfbits(v.y); o.z = bfbits(v.z); o.w = bfbits(v.w);
  dst[t] = o;
}

// ---------------- im2col: x(16,3,224,224) f32 -> A0[3136,768] bf16 ----------------
__global__ void im2col_kernel(const float* __restrict__ x,
                              __hip_bfloat16* __restrict__ A0) {
  int t = blockIdx.x * 256 + threadIdx.x;   // 150528 = 3136*3*16 exact
  int kh = t & 15;
  int rest = t >> 4;
  int c = rest % 3;
  int row = rest / 3;          // 0..3135
  int b = row / 196;
  int ij = row - b * 196;
  int i = ij / 14;
  int j = ij - i * 14;
  const float4* s4 = reinterpret_cast<const float4*>(
      x + ((size_t)(b * 3 + c) * 224 + (size_t)(i * 16 + kh)) * 224 + j * 16);
  __hip_bfloat16* dst = A0 + (size_t)row * 768 + c * 256 + kh * 16;
  float4 v0 = s4[0], v1 = s4[1], v2 = s4[2], v3 = s4[3];
  ushort8 o0, o1;
  o0[0] = bfbits(v0.x); o0[1] = bfbits(v0.y); o0[2] = bfbits(v0.z); o0[3] = bfbits(v0.w);
  o0[4] = bfbits(v1.x); o0[5] = bfbits(v1.y); o0[6] = bfbits(v1.z); o0[7] = bfbits(v1.w);
  o1[0] = bfbits(v2.x); o1[1] = bfbits(v2.y); o1[2] = bfbits(v2.z); o1[3] = bfbits(v2.w);
  o1[4] = bfbits(v3.x); o1[5] = bfbits(v3.y); o1[6] = bfbits(v3.z); o1[7] = bfbits(v3.w);
  ushort8* d8 = reinterpret_cast<ushort8*>(dst);
  d8[0] = o0;
  d8[1] = o1;
}

// ---------------- L0 GEMM: f = relu(A0[3136,768] * Wf[512,768]^T + bf) ----------------
// One wave per 64x64 tile. MFMA 16x16x32 bf16.
__global__ void gemm_bt(const __hip_bfloat16* __restrict__ A,
                        const __hip_bfloat16* __restrict__ W,
                        const float* __restrict__ bias,
                        __hip_bfloat16* __restrict__ C,
                        int M, int N, int K) {
  const int m0 = blockIdx.x * 64;
  const int n0 = blockIdx.y * 64;
  const int lane = threadIdx.x;      // 0..63
  const int r = lane & 15;
  const int q = lane >> 4;

  const __hip_bfloat16* Abase = A + (size_t)(m0 + r) * K + q * 8;
  const __hip_bfloat16* Wbase = W + (size_t)(n0 + r) * K + q * 8;

  floatx4 acc[4][4] = {};
  for (int k = 0; k < K; k += 32) {
    short8 a[4], b[4];
#pragma unroll
    for (int i = 0; i < 4; ++i) {
      a[i] = *reinterpret_cast<const short8*>(Abase + (size_t)i * 16 * K + k);
      b[i] = *reinterpret_cast<const short8*>(Wbase + (size_t)i * 16 * K + k);
    }
#pragma unroll
    for (int mi = 0; mi < 4; ++mi)
#pragma unroll
      for (int ni = 0; ni < 4; ++ni)
        acc[mi][ni] = __builtin_amdgcn_mfma_f32_16x16x32_bf16(a[mi], b[ni], acc[mi][ni], 0, 0, 0);
  }

#pragma unroll
  for (int mi = 0; mi < 4; ++mi) {
#pragma unroll
    for (int ni = 0; ni < 4; ++ni) {
      int col = n0 + ni * 16 + r;
      float bv = bias[col];
#pragma unroll
      for (int rr = 0; rr < 4; ++rr) {
        int row = m0 + mi * 16 + q * 4 + rr;
        float v = fmaxf(acc[mi][ni][rr] + bv, 0.0f);
        C[(size_t)row * N + col] = __float2bfloat16(v);
      }
    }
  }
}

// ---------------- fused L1..L4 + distances + act ----------------
// Block = 16 positions, 4 waves. Intermediates in LDS (f32).
// bufA: h1 [16][260] -> later h3 [16][132]
// bufB: h2 [16][260] -> later h4 [16][132]
// ps:   protos [60][132]
__device__ __forceinline__ short8 frag_from_lds(const float* p) {
  float4 f0 = *reinterpret_cast<const float4*>(p);
  float4 f1 = *reinterpret_cast<const float4*>(p + 4);
  short8 a;
  a[0] = bfbits(f0.x); a[1] = bfbits(f0.y); a[2] = bfbits(f0.z); a[3] = bfbits(f0.w);
  a[4] = bfbits(f1.x); a[5] = bfbits(f1.y); a[6] = bfbits(f1.z); a[7] = bfbits(f1.w);
  return a;
}

template <int N, int K, int ACT>
__device__ __forceinline__ void layer_lds(const float* __restrict__ A, int astride,
                                          const __hip_bfloat16* __restrict__ W,
                                          const float* __restrict__ bias,
                                          float* __restrict__ C, int cstride,
                                          int w, int r, int q) {
  constexpr int NA = N / 64;       // accumulators per wave (wave covers N/4 cols)
  const int n0 = w * (N / 4);
  floatx4 acc[NA] = {};
#pragma unroll
  for (int k0 = 0; k0 < K; k0 += 32) {
    short8 a = frag_from_lds(A + r * astride + k0 + q * 8);
#pragma unroll
    for (int ni = 0; ni < NA; ++ni) {
      short8 b = *reinterpret_cast<const short8*>(W + (size_t)(n0 + ni * 16 + r) * K + k0 + q * 8);
      acc[ni] = __builtin_amdgcn_mfma_f32_16x16x32_bf16(a, b, acc[ni], 0, 0, 0);
    }
  }
#pragma unroll
  for (int ni = 0; ni < NA; ++ni) {
    float bv = bias[n0 + ni * 16 + r];
#pragma unroll
    for (int rr = 0; rr < 4; ++rr) {
      float v = acc[ni][rr] + bv;
      v = (ACT == 0) ? fmaxf(v, 0.0f) : 1.0f / (1.0f + __expf(-v));
      C[(q * 4 + rr) * cstride + n0 + ni * 16 + r] = v;
    }
  }
}

__global__ __launch_bounds__(256) void mlp_dist_kernel(
    const __hip_bfloat16* __restrict__ f,
    const __hip_bfloat16* __restrict__ W1B, const float* __restrict__ b1,
    const __hip_bfloat16* __restrict__ W2B, const float* __restrict__ b2,
    const __hip_bfloat16* __restrict__ W3B, const float* __restrict__ b3,
    const __hip_bfloat16* __restrict__ W4B, const float* __restrict__ b4,
    const float* __restrict__ proto,
    float* __restrict__ dist, float* __restrict__ act) {
  __shared__ float bufA[16 * 260];
  __shared__ float bufB[16 * 260];
  __shared__ float ps[60 * 132];
  const int t = threadIdx.x;
  const int w = t >> 6;
  const int lane = t & 63;
  const int r = lane & 15;
  const int q = lane >> 4;
  const int pos0 = blockIdx.x * 16;    // 196 blocks

  // stage prototypes (f32, padded stride 132)
  {
    const float4* p4 = reinterpret_cast<const float4*>(proto);
    for (int i = t; i < 1920; i += 256) {
      int p = i >> 5, kc = i & 31;
      *reinterpret_cast<float4*>(&ps[p * 132 + kc * 4]) = p4[i];
    }
  }

  // L1: h1 = relu(f * W1^T), M=16, N=256, K=512, A from GLOBAL f
  {
    const __hip_bfloat16* Ab = f + (size_t)(pos0 + r) * 512 + q * 8;
    floatx4 acc[4] = {};
#pragma unroll
    for (int k0 = 0; k0 < 512; k0 += 32) {
      short8 a = *reinterpret_cast<const short8*>(Ab + k0);
#pragma unroll
      for (int ni = 0; ni < 4; ++ni) {
        short8 b = *reinterpret_cast<const short8*>(W1B + (size_t)(w * 64 + ni * 16 + r) * 512 + k0 + q * 8);
        acc[ni] = __builtin_amdgcn_mfma_f32_16x16x32_bf16(a, b, acc[ni], 0, 0, 0);
      }
    }
#pragma unroll
    for (int ni = 0; ni < 4; ++ni) {
      float bv = b1[w * 64 + ni * 16 + r];
#pragma unroll
      for (int rr = 0; rr < 4; ++rr) {
        float v = fmaxf(acc[ni][rr] + bv, 0.0f);
        bufA[(q * 4 + rr) * 260 + w * 64 + ni * 16 + r] = v;
      }
    }
  }
  __syncthreads();
  // L2: h2 = relu(h1 * W2^T), N=256, K=256
  layer_lds<256, 256, 0>(bufA, 260, W2B, b2, bufB, 260, w, r, q);
  __syncthreads();
  // L3: h3 = relu(h2 * W3^T), N=128, K=256  (bufA reused, stride 132)
  layer_lds<128, 256, 0>(bufB, 260, W3B, b3, bufA, 132, w, r, q);
  __syncthreads();
  // L4: h4 = sigmoid(h3 * W4^T), N=128, K=128 (bufB reused, stride 132)
  layer_lds<128, 128, 1>(bufA, 132, W4B, b4, bufB, 132, w, r, q);
  __syncthreads();

  // distances + act from LDS h4 (bufB) and ps
  for (int qq = t; qq < 960; qq += 256) {
    int p = qq >> 4;          // 0..59
    int pos = qq & 15;
    float s = 0.0f;
#pragma unroll 8
    for (int k = 0; k < 128; ++k) {
      float dv = bufB[pos * 132 + k] - ps[p * 132 + k];
      s = fmaf(dv, dv, s);
    }
    float d = sqrtf(s);
    float a = __logf((d + 1.0f) / (d + EPSV));
    int gpos = pos0 + pos;
    int bimg = gpos / 196;
    int hw = gpos - bimg * 196;
    size_t idx = ((size_t)bimg * 60 + p) * 196 + hw;
    dist[idx] = d;
    act[idx] = a;
  }
}

// ---------------- top-5 smallest distances per (b,p): one WAVE per unit ----------------
__global__ void topk_kernel(const float* __restrict__ dist,
                            float* __restrict__ proto_act,
                            float* __restrict__ out_mind) {
  const int wid = threadIdx.x >> 6;
  const int lane = threadIdx.x & 63;
  const int u = blockIdx.x * 4 + wid;          // 0..959 exact (240 blocks)
  const float* rowp = dist + (size_t)u * 196;

  float v[4];
#pragma unroll
  for (int i = 0; i < 4; ++i) {
    int idx = lane + 64 * i;
    v[i] = (idx < 196) ? rowp[idx] : 1e30f;
  }

  float sd = 0.0f, sa = 0.0f;
#pragma unroll
  for (int round = 0; round < 5; ++round) {
    float lmin = fminf(fminf(v[0], v[1]), fminf(v[2], v[3]));
    float m = lmin;
#pragma unroll
    for (int off = 32; off >= 1; off >>= 1)
      m = fminf(m, __shfl_xor(m, off));
    unsigned long long msk = __ballot(lmin == m);
    int leader = __ffsll((long long)msk) - 1;
    if (lane == leader) {
      if (v[0] == m)      v[0] = 1e30f;
      else if (v[1] == m) v[1] = 1e30f;
      else if (v[2] == m) v[2] = 1e30f;
      else                v[3] = 1e30f;
    }
    sd += m;
    sa += __logf((m + 1.0f) / (m + EPSV));
  }
  if (lane == 0) {
    out_mind[u] = sd * 0.2f;
    proto_act[u] = sa * 0.2f;
  }
}

// ---------------- logits[16,3] = proto_act[16,60] @ last_W[3,60]^T ----------------
__global__ void logits_kernel(const float* __restrict__ proto_act,
                              const float* __restrict__ lastW,
                              float* __restrict__ out) {
  int t = threadIdx.x;
  if (t < 48) {
    int b = t / 3, c = t - b * 3;
    float s = 0.0f;
    for (int p = 0; p < 60; ++p)
      s += proto_act[b * 60 + p] * lastW[c * 60 + p];
    out[t] = s;
  }
}

// ---------------- upsample 16x: act[16,60,14,14] f32 -> out[16,60,224,224] f32 ----------------
__global__ void upsample_kernel(const float* __restrict__ act,
                                float* __restrict__ up) {
  int t = blockIdx.x * 256 + threadIdx.x;   // 12,057,600 exact (47100 blocks)
  int col4 = t % 56;
  int rem = t / 56;
  int y = rem % 224;
  int bp = rem / 224;
  float v = act[(size_t)bp * 196 + (y >> 4) * 14 + (col4 >> 2)];
  float4 val;
  val.x = v; val.y = v; val.z = v; val.w = v;
  reinterpret_cast<float4*>(up)[t] = val;
}

extern "C" void kernel_launch(void* const* d_in, const int* in_sizes, int n_in,
                              void* d_out, int out_size, void* d_ws, size_t ws_size,
                              hipStream_t stream) {
  const float* x     = (const float*)d_in[0];
  const float* Wf    = (const float*)d_in[2];   // [512,768]
  const float* bf    = (const float*)d_in[3];
  const float* W1    = (const float*)d_in[4];   // [256,512]
  const float* b1    = (const float*)d_in[5];
  const float* W2    = (const float*)d_in[6];   // [256,256]
  const float* b2    = (const float*)d_in[7];
  const float* W3    = (const float*)d_in[8];   // [128,256]
  const float* b3    = (const float*)d_in[9];
  const float* W4    = (const float*)d_in[10];  // [128,128]
  const float* b4    = (const float*)d_in[11];
  const float* proto = (const float*)d_in[12];  // [60,128]
  const float* lastW = (const float*)d_in[13];  // [3,60]

  char* ws = (char*)d_ws;
  __hip_bfloat16* WfB = (__hip_bfloat16*)(ws + 0);         // 393216 elems
  __hip_bfloat16* W1B = (__hip_bfloat16*)(ws + 786432);    // 131072
  __hip_bfloat16* W2B = (__hip_bfloat16*)(ws + 1048576);   // 65536
  __hip_bfloat16* W3B = (__hip_bfloat16*)(ws + 1179648);   // 32768
  __hip_bfloat16* W4B = (__hip_bfloat16*)(ws + 1245184);   // 16384
  __hip_bfloat16* A0 = (__hip_bfloat16*)(ws + 1310720);    // [3136,768] bf16
  __hip_bfloat16* f  = (__hip_bfloat16*)(ws + 6128128);    // [3136,512] bf16
  float* dist = (float*)(ws + 9339392);                    // [960,196] f32
  float* act  = (float*)(ws + 10092032);                   // [960,196] f32
  float* pact = (float*)(ws + 10844672);                   // [960] f32

  float* out        = (float*)d_out;
  float* out_logits = out;          // 48
  float* out_mind   = out + 48;     // 960
  float* out_up     = out + 1008;   // 48,230,400

  cvt_weights<<<624, 256, 0, stream>>>((const float4*)Wf, (const float4*)W1,
                                       (const float4*)W2, (const float4*)W3,
                                       (const float4*)W4, (ushort4*)WfB);
  im2col_kernel<<<588, 256, 0, stream>>>(x, A0);
  gemm_bt<<<dim3(49, 8), 64, 0, stream>>>(A0, WfB, bf, f, 3136, 512, 768);
  mlp_dist_kernel<<<196, 256, 0, stream>>>(f, W1B, b1, W2B, b2, W3B, b3, W4B, b4,
                                           proto, dist, act);
  topk_kernel<<<240, 256, 0, stream>>>(dist, pact, out_mind);
  logits_kernel<<<1, 64, 0, stream>>>(pact, lastW, out_logits);
  upsample_kernel<<<47100, 256, 0, stream>>>(act, out_up);
}

// Round 5
// 279.681 us; speedup vs baseline: 1.7326x; 1.0227x over previous
//
#include <hip/hip_runtime.h>
#include <hip/hip_bf16.h>

using short8  = __attribute__((ext_vector_type(8))) short;
using ushort8 = __attribute__((ext_vector_type(8))) unsigned short;
using floatx4 = __attribute__((ext_vector_type(4))) float;

#define EPSV 1e-4f

__device__ __forceinline__ unsigned short bfbits(float f) {
  __hip_bfloat16 h = __float2bfloat16(f);
  return *reinterpret_cast<unsigned short*>(&h);
}

// ---------------- prep: weight cvt (blocks 0..623) + im2col (blocks 624..1211) ----------------
__global__ void prep_kernel(const float4* __restrict__ Wf, const float4* __restrict__ W1,
                            const float4* __restrict__ W2, const float4* __restrict__ W3,
                            const float4* __restrict__ W4, ushort4* __restrict__ wdst,
                            const float* __restrict__ x, __hip_bfloat16* __restrict__ A0) {
  if (blockIdx.x < 624) {
    int t = blockIdx.x * 256 + threadIdx.x;   // 159744 exact
    const float4* src; int off;
    if (t < 98304)       { src = Wf; off = 0; }
    else if (t < 131072) { src = W1; off = 98304; }
    else if (t < 147456) { src = W2; off = 131072; }
    else if (t < 155648) { src = W3; off = 147456; }
    else                 { src = W4; off = 155648; }
    float4 v = src[t - off];
    ushort4 o;
    o.x = bfbits(v.x); o.y = bfbits(v.y); o.z = bfbits(v.z); o.w = bfbits(v.w);
    wdst[t] = o;
  } else {
    int t = (blockIdx.x - 624) * 256 + threadIdx.x;   // 150528 = 3136*3*16 exact
    int kh = t & 15;
    int rest = t >> 4;
    int c = rest % 3;
    int row = rest / 3;          // 0..3135
    int b = row / 196;
    int ij = row - b * 196;
    int i = ij / 14;
    int j = ij - i * 14;
    const float4* s4 = reinterpret_cast<const float4*>(
        x + ((size_t)(b * 3 + c) * 224 + (size_t)(i * 16 + kh)) * 224 + j * 16);
    __hip_bfloat16* dst = A0 + (size_t)row * 768 + c * 256 + kh * 16;
    float4 v0 = s4[0], v1 = s4[1], v2 = s4[2], v3 = s4[3];
    ushort8 o0, o1;
    o0[0] = bfbits(v0.x); o0[1] = bfbits(v0.y); o0[2] = bfbits(v0.z); o0[3] = bfbits(v0.w);
    o0[4] = bfbits(v1.x); o0[5] = bfbits(v1.y); o0[6] = bfbits(v1.z); o0[7] = bfbits(v1.w);
    o1[0] = bfbits(v2.x); o1[1] = bfbits(v2.y); o1[2] = bfbits(v2.z); o1[3] = bfbits(v2.w);
    o1[4] = bfbits(v3.x); o1[5] = bfbits(v3.y); o1[6] = bfbits(v3.z); o1[7] = bfbits(v3.w);
    ushort8* d8 = reinterpret_cast<ushort8*>(dst);
    d8[0] = o0;
    d8[1] = o1;
  }
}

// ---------------- L0 GEMM: f = relu(A0[3136,768] * Wf[512,768]^T + bf) ----------------
// One wave per 64x64 tile. MFMA 16x16x32 bf16. Compile-time K for pipelining.
template <int K>
__global__ void gemm_bt(const __hip_bfloat16* __restrict__ A,
                        const __hip_bfloat16* __restrict__ W,
                        const float* __restrict__ bias,
                        __hip_bfloat16* __restrict__ C,
                        int M, int N) {
  const int m0 = blockIdx.x * 64;
  const int n0 = blockIdx.y * 64;
  const int lane = threadIdx.x;      // 0..63
  const int r = lane & 15;
  const int q = lane >> 4;

  const __hip_bfloat16* Abase = A + (size_t)(m0 + r) * K + q * 8;
  const __hip_bfloat16* Wbase = W + (size_t)(n0 + r) * K + q * 8;

  floatx4 acc[4][4] = {};
#pragma unroll 4
  for (int k = 0; k < K; k += 32) {
    short8 a[4], b[4];
#pragma unroll
    for (int i = 0; i < 4; ++i) {
      a[i] = *reinterpret_cast<const short8*>(Abase + (size_t)i * 16 * K + k);
      b[i] = *reinterpret_cast<const short8*>(Wbase + (size_t)i * 16 * K + k);
    }
#pragma unroll
    for (int mi = 0; mi < 4; ++mi)
#pragma unroll
      for (int ni = 0; ni < 4; ++ni)
        acc[mi][ni] = __builtin_amdgcn_mfma_f32_16x16x32_bf16(a[mi], b[ni], acc[mi][ni], 0, 0, 0);
  }

#pragma unroll
  for (int mi = 0; mi < 4; ++mi) {
#pragma unroll
    for (int ni = 0; ni < 4; ++ni) {
      int col = n0 + ni * 16 + r;
      float bv = bias[col];
#pragma unroll
      for (int rr = 0; rr < 4; ++rr) {
        int row = m0 + mi * 16 + q * 4 + rr;
        float v = fmaxf(acc[mi][ni][rr] + bv, 0.0f);
        C[(size_t)row * N + col] = __float2bfloat16(v);
      }
    }
  }
}

// ---------------- fused L1..L4 + distances + act ----------------
__device__ __forceinline__ short8 frag_from_lds(const float* p) {
  float4 f0 = *reinterpret_cast<const float4*>(p);
  float4 f1 = *reinterpret_cast<const float4*>(p + 4);
  short8 a;
  a[0] = bfbits(f0.x); a[1] = bfbits(f0.y); a[2] = bfbits(f0.z); a[3] = bfbits(f0.w);
  a[4] = bfbits(f1.x); a[5] = bfbits(f1.y); a[6] = bfbits(f1.z); a[7] = bfbits(f1.w);
  return a;
}

template <int N, int K, int ACT>
__device__ __forceinline__ void layer_lds(const float* __restrict__ A, int astride,
                                          const __hip_bfloat16* __restrict__ W,
                                          const float* __restrict__ bias,
                                          float* __restrict__ C, int cstride,
                                          int w, int r, int q) {
  constexpr int NA = N / 64;
  const int n0 = w * (N / 4);
  floatx4 acc[NA] = {};
#pragma unroll
  for (int k0 = 0; k0 < K; k0 += 32) {
    short8 a = frag_from_lds(A + r * astride + k0 + q * 8);
#pragma unroll
    for (int ni = 0; ni < NA; ++ni) {
      short8 b = *reinterpret_cast<const short8*>(W + (size_t)(n0 + ni * 16 + r) * K + k0 + q * 8);
      acc[ni] = __builtin_amdgcn_mfma_f32_16x16x32_bf16(a, b, acc[ni], 0, 0, 0);
    }
  }
#pragma unroll
  for (int ni = 0; ni < NA; ++ni) {
    float bv = bias[n0 + ni * 16 + r];
#pragma unroll
    for (int rr = 0; rr < 4; ++rr) {
      float v = acc[ni][rr] + bv;
      v = (ACT == 0) ? fmaxf(v, 0.0f) : 1.0f / (1.0f + __expf(-v));
      C[(q * 4 + rr) * cstride + n0 + ni * 16 + r] = v;
    }
  }
}

__global__ __launch_bounds__(256) void mlp_dist_kernel(
    const __hip_bfloat16* __restrict__ f,
    const __hip_bfloat16* __restrict__ W1B, const float* __restrict__ b1,
    const __hip_bfloat16* __restrict__ W2B, const float* __restrict__ b2,
    const __hip_bfloat16* __restrict__ W3B, const float* __restrict__ b3,
    const __hip_bfloat16* __restrict__ W4B, const float* __restrict__ b4,
    const float* __restrict__ proto,
    float* __restrict__ dist, float* __restrict__ act) {
  __shared__ float bufA[16 * 260];
  __shared__ float bufB[16 * 260];
  __shared__ float ps[60 * 132];
  const int t = threadIdx.x;
  const int w = t >> 6;
  const int lane = t & 63;
  const int r = lane & 15;
  const int q = lane >> 4;
  const int pos0 = blockIdx.x * 16;    // 196 blocks

  // stage prototypes (f32, padded stride 132)
  {
    const float4* p4 = reinterpret_cast<const float4*>(proto);
    for (int i = t; i < 1920; i += 256) {
      int p = i >> 5, kc = i & 31;
      *reinterpret_cast<float4*>(&ps[p * 132 + kc * 4]) = p4[i];
    }
  }

  // L1: h1 = relu(f * W1^T), M=16, N=256, K=512, A from GLOBAL f
  {
    const __hip_bfloat16* Ab = f + (size_t)(pos0 + r) * 512 + q * 8;
    floatx4 acc[4] = {};
#pragma unroll
    for (int k0 = 0; k0 < 512; k0 += 32) {
      short8 a = *reinterpret_cast<const short8*>(Ab + k0);
#pragma unroll
      for (int ni = 0; ni < 4; ++ni) {
        short8 b = *reinterpret_cast<const short8*>(W1B + (size_t)(w * 64 + ni * 16 + r) * 512 + k0 + q * 8);
        acc[ni] = __builtin_amdgcn_mfma_f32_16x16x32_bf16(a, b, acc[ni], 0, 0, 0);
      }
    }
#pragma unroll
    for (int ni = 0; ni < 4; ++ni) {
      float bv = b1[w * 64 + ni * 16 + r];
#pragma unroll
      for (int rr = 0; rr < 4; ++rr) {
        float v = fmaxf(acc[ni][rr] + bv, 0.0f);
        bufA[(q * 4 + rr) * 260 + w * 64 + ni * 16 + r] = v;
      }
    }
  }
  __syncthreads();
  layer_lds<256, 256, 0>(bufA, 260, W2B, b2, bufB, 260, w, r, q);
  __syncthreads();
  layer_lds<128, 256, 0>(bufB, 260, W3B, b3, bufA, 132, w, r, q);
  __syncthreads();
  layer_lds<128, 128, 1>(bufA, 132, W4B, b4, bufB, 132, w, r, q);
  __syncthreads();

  // distances + act from LDS h4 (bufB) and ps — float4 vectorized
  for (int qq = t; qq < 960; qq += 256) {
    int p = qq >> 4;          // 0..59
    int pos = qq & 15;
    const float4* hv4 = reinterpret_cast<const float4*>(&bufB[pos * 132]);
    const float4* pv4 = reinterpret_cast<const float4*>(&ps[p * 132]);
    float s = 0.0f;
#pragma unroll 8
    for (int k = 0; k < 32; ++k) {
      float4 hv = hv4[k];
      float4 pv = pv4[k];
      float d0 = hv.x - pv.x, d1 = hv.y - pv.y, d2 = hv.z - pv.z, d3 = hv.w - pv.w;
      s = fmaf(d0, d0, s); s = fmaf(d1, d1, s); s = fmaf(d2, d2, s); s = fmaf(d3, d3, s);
    }
    float d = sqrtf(s);
    float a = __logf((d + 1.0f) / (d + EPSV));
    int gpos = pos0 + pos;
    int bimg = gpos / 196;
    int hw = gpos - bimg * 196;
    size_t idx = ((size_t)bimg * 60 + p) * 196 + hw;
    dist[idx] = d;
    act[idx] = a;
  }
}

// ---------------- top-5 smallest distances per (b,p): one WAVE per unit ----------------
__global__ void topk_kernel(const float* __restrict__ dist,
                            float* __restrict__ proto_act,
                            float* __restrict__ out_mind) {
  const int wid = threadIdx.x >> 6;
  const int lane = threadIdx.x & 63;
  const int u = blockIdx.x * 4 + wid;          // 0..959 exact (240 blocks)
  const float* rowp = dist + (size_t)u * 196;

  float v[4];
#pragma unroll
  for (int i = 0; i < 4; ++i) {
    int idx = lane + 64 * i;
    v[i] = (idx < 196) ? rowp[idx] : 1e30f;
  }

  float sd = 0.0f, sa = 0.0f;
#pragma unroll
  for (int round = 0; round < 5; ++round) {
    float lmin = fminf(fminf(v[0], v[1]), fminf(v[2], v[3]));
    float m = lmin;
#pragma unroll
    for (int off = 32; off >= 1; off >>= 1)
      m = fminf(m, __shfl_xor(m, off));
    unsigned long long msk = __ballot(lmin == m);
    int leader = __ffsll((long long)msk) - 1;
    if (lane == leader) {
      if (v[0] == m)      v[0] = 1e30f;
      else if (v[1] == m) v[1] = 1e30f;
      else if (v[2] == m) v[2] = 1e30f;
      else                v[3] = 1e30f;
    }
    sd += m;
    sa += __logf((m + 1.0f) / (m + EPSV));
  }
  if (lane == 0) {
    out_mind[u] = sd * 0.2f;
    proto_act[u] = sa * 0.2f;
  }
}

// ---------------- upsample 16x + logits tail block ----------------
__global__ void upsample_kernel(const float* __restrict__ act,
                                float* __restrict__ up,
                                const float* __restrict__ proto_act,
                                const float* __restrict__ lastW,
                                float* __restrict__ out_logits) {
  if (blockIdx.x < 47100) {
    int t = blockIdx.x * 256 + threadIdx.x;   // 12,057,600 exact
    int col4 = t % 56;
    int rem = t / 56;
    int y = rem % 224;
    int bp = rem / 224;
    float v = act[(size_t)bp * 196 + (y >> 4) * 14 + (col4 >> 2)];
    float4 val;
    val.x = v; val.y = v; val.z = v; val.w = v;
    reinterpret_cast<float4*>(up)[t] = val;
  } else {
    int t = threadIdx.x;
    if (t < 48) {
      int b = t / 3, c = t - b * 3;
      float s = 0.0f;
      for (int p = 0; p < 60; ++p)
        s += proto_act[b * 60 + p] * lastW[c * 60 + p];
      out_logits[t] = s;
    }
  }
}

extern "C" void kernel_launch(void* const* d_in, const int* in_sizes, int n_in,
                              void* d_out, int out_size, void* d_ws, size_t ws_size,
                              hipStream_t stream) {
  const float* x     = (const float*)d_in[0];
  const float* Wf    = (const float*)d_in[2];   // [512,768]
  const float* bf    = (const float*)d_in[3];
  const float* W1    = (const float*)d_in[4];   // [256,512]
  const float* b1    = (const float*)d_in[5];
  const float* W2    = (const float*)d_in[6];   // [256,256]
  const float* b2    = (const float*)d_in[7];
  const float* W3    = (const float*)d_in[8];   // [128,256]
  const float* b3    = (const float*)d_in[9];
  const float* W4    = (const float*)d_in[10];  // [128,128]
  const float* b4    = (const float*)d_in[11];
  const float* proto = (const float*)d_in[12];  // [60,128]
  const float* lastW = (const float*)d_in[13];  // [3,60]

  char* ws = (char*)d_ws;
  __hip_bfloat16* WfB = (__hip_bfloat16*)(ws + 0);         // 393216 elems
  __hip_bfloat16* W1B = (__hip_bfloat16*)(ws + 786432);    // 131072
  __hip_bfloat16* W2B = (__hip_bfloat16*)(ws + 1048576);   // 65536
  __hip_bfloat16* W3B = (__hip_bfloat16*)(ws + 1179648);   // 32768
  __hip_bfloat16* W4B = (__hip_bfloat16*)(ws + 1245184);   // 16384
  __hip_bfloat16* A0 = (__hip_bfloat16*)(ws + 1310720);    // [3136,768] bf16
  __hip_bfloat16* f  = (__hip_bfloat16*)(ws + 6128128);    // [3136,512] bf16
  float* dist = (float*)(ws + 9339392);                    // [960,196] f32
  float* act  = (float*)(ws + 10092032);                   // [960,196] f32
  float* pact = (float*)(ws + 10844672);                   // [960] f32

  float* out        = (float*)d_out;
  float* out_logits = out;          // 48
  float* out_mind   = out + 48;     // 960
  float* out_up     = out + 1008;   // 48,230,400

  prep_kernel<<<1212, 256, 0, stream>>>((const float4*)Wf, (const float4*)W1,
                                        (const float4*)W2, (const float4*)W3,
                                        (const float4*)W4, (ushort4*)WfB, x, A0);
  gemm_bt<768><<<dim3(49, 8), 64, 0, stream>>>(A0, WfB, bf, f, 3136, 512);
  mlp_dist_kernel<<<196, 256, 0, stream>>>(f, W1B, b1, W2B, b2, W3B, b3, W4B, b4,
                                           proto, dist, act);
  topk_kernel<<<240, 256, 0, stream>>>(dist, pact, out_mind);
  upsample_kernel<<<47101, 256, 0, stream>>>(act, out_up, pact, lastW, out_logits);
}

// Round 6
// 273.952 us; speedup vs baseline: 1.7689x; 1.0209x over previous
//
#include <hip/hip_runtime.h>
#include <hip/hip_bf16.h>

using short8  = __attribute__((ext_vector_type(8))) short;
using ushort8 = __attribute__((ext_vector_type(8))) unsigned short;
using floatx4 = __attribute__((ext_vector_type(4))) float;

#define EPSV 1e-4f

__device__ __forceinline__ unsigned short bfbits(float f) {
  __hip_bfloat16 h = __float2bfloat16(f);
  return *reinterpret_cast<unsigned short*>(&h);
}

// ---------------- prep: weight cvt (blocks 0..623) + im2col (blocks 624..1211) ----------------
__global__ void prep_kernel(const float4* __restrict__ Wf, const float4* __restrict__ W1,
                            const float4* __restrict__ W2, const float4* __restrict__ W3,
                            const float4* __restrict__ W4, ushort4* __restrict__ wdst,
                            const float* __restrict__ x, __hip_bfloat16* __restrict__ A0) {
  if (blockIdx.x < 624) {
    int t = blockIdx.x * 256 + threadIdx.x;   // 159744 exact
    const float4* src; int off;
    if (t < 98304)       { src = Wf; off = 0; }
    else if (t < 131072) { src = W1; off = 98304; }
    else if (t < 147456) { src = W2; off = 131072; }
    else if (t < 155648) { src = W3; off = 147456; }
    else                 { src = W4; off = 155648; }
    float4 v = src[t - off];
    ushort4 o;
    o.x = bfbits(v.x); o.y = bfbits(v.y); o.z = bfbits(v.z); o.w = bfbits(v.w);
    wdst[t] = o;
  } else {
    int t = (blockIdx.x - 624) * 256 + threadIdx.x;   // 150528 = 3136*3*16 exact
    int kh = t & 15;
    int rest = t >> 4;
    int c = rest % 3;
    int row = rest / 3;          // 0..3135
    int b = row / 196;
    int ij = row - b * 196;
    int i = ij / 14;
    int j = ij - i * 14;
    const float4* s4 = reinterpret_cast<const float4*>(
        x + ((size_t)(b * 3 + c) * 224 + (size_t)(i * 16 + kh)) * 224 + j * 16);
    __hip_bfloat16* dst = A0 + (size_t)row * 768 + c * 256 + kh * 16;
    float4 v0 = s4[0], v1 = s4[1], v2 = s4[2], v3 = s4[3];
    ushort8 o0, o1;
    o0[0] = bfbits(v0.x); o0[1] = bfbits(v0.y); o0[2] = bfbits(v0.z); o0[3] = bfbits(v0.w);
    o0[4] = bfbits(v1.x); o0[5] = bfbits(v1.y); o0[6] = bfbits(v1.z); o0[7] = bfbits(v1.w);
    o1[0] = bfbits(v2.x); o1[1] = bfbits(v2.y); o1[2] = bfbits(v2.z); o1[3] = bfbits(v2.w);
    o1[4] = bfbits(v3.x); o1[5] = bfbits(v3.y); o1[6] = bfbits(v3.z); o1[7] = bfbits(v3.w);
    ushort8* d8 = reinterpret_cast<ushort8*>(dst);
    d8[0] = o0;
    d8[1] = o1;
  }
}

// ---------------- fused L0..L4 + distances + act ----------------
__device__ __forceinline__ short8 frag_from_lds(const float* p) {
  float4 f0 = *reinterpret_cast<const float4*>(p);
  float4 f1 = *reinterpret_cast<const float4*>(p + 4);
  short8 a;
  a[0] = bfbits(f0.x); a[1] = bfbits(f0.y); a[2] = bfbits(f0.z); a[3] = bfbits(f0.w);
  a[4] = bfbits(f1.x); a[5] = bfbits(f1.y); a[6] = bfbits(f1.z); a[7] = bfbits(f1.w);
  return a;
}

template <int N, int K, int ACT>
__device__ __forceinline__ void layer_lds(const float* __restrict__ A, int astride,
                                          const __hip_bfloat16* __restrict__ W,
                                          const float* __restrict__ bias,
                                          float* __restrict__ C, int cstride,
                                          int w, int r, int q) {
  constexpr int NA = N / 64;
  const int n0 = w * (N / 4);
  floatx4 acc[NA] = {};
#pragma unroll
  for (int k0 = 0; k0 < K; k0 += 32) {
    short8 a = frag_from_lds(A + r * astride + k0 + q * 8);
#pragma unroll
    for (int ni = 0; ni < NA; ++ni) {
      short8 b = *reinterpret_cast<const short8*>(W + (size_t)(n0 + ni * 16 + r) * K + k0 + q * 8);
      acc[ni] = __builtin_amdgcn_mfma_f32_16x16x32_bf16(a, b, acc[ni], 0, 0, 0);
    }
  }
#pragma unroll
  for (int ni = 0; ni < NA; ++ni) {
    float bv = bias[n0 + ni * 16 + r];
#pragma unroll
    for (int rr = 0; rr < 4; ++rr) {
      float v = acc[ni][rr] + bv;
      v = (ACT == 0) ? fmaxf(v, 0.0f) : 1.0f / (1.0f + __expf(-v));
      C[(q * 4 + rr) * cstride + n0 + ni * 16 + r] = v;
    }
  }
}

__global__ __launch_bounds__(256) void mlp_dist_kernel(
    const __hip_bfloat16* __restrict__ A0,
    const __hip_bfloat16* __restrict__ WfB, const float* __restrict__ bias0,
    const __hip_bfloat16* __restrict__ W1B, const float* __restrict__ b1,
    const __hip_bfloat16* __restrict__ W2B, const float* __restrict__ b2,
    const __hip_bfloat16* __restrict__ W3B, const float* __restrict__ b3,
    const __hip_bfloat16* __restrict__ W4B, const float* __restrict__ b4,
    const float* __restrict__ proto,
    float* __restrict__ dist, float* __restrict__ act) {
  __shared__ float bufF[16 * 516];   // f (L0 out, f32), stride 516 -> 2-way bank alias only
  __shared__ float bufA[16 * 260];
  __shared__ float bufB[16 * 260];
  __shared__ float ps[60 * 132];
  const int t = threadIdx.x;
  const int w = t >> 6;
  const int lane = t & 63;
  const int r = lane & 15;
  const int q = lane >> 4;
  const int pos0 = blockIdx.x * 16;    // 196 blocks

  // stage prototypes (f32, padded stride 132)
  {
    const float4* p4 = reinterpret_cast<const float4*>(proto);
    for (int i = t; i < 1920; i += 256) {
      int p = i >> 5, kc = i & 31;
      *reinterpret_cast<float4*>(&ps[p * 132 + kc * 4]) = p4[i];
    }
  }

  // L0: f = relu(A0 * Wf^T + bf), M=16 pos, N=512, K=768; wave w covers cols w*128..+127
  {
    const __hip_bfloat16* Ab = A0 + (size_t)(pos0 + r) * 768 + q * 8;
    floatx4 acc[8] = {};
#pragma unroll 4
    for (int k0 = 0; k0 < 768; k0 += 32) {
      short8 a = *reinterpret_cast<const short8*>(Ab + k0);
#pragma unroll
      for (int ni = 0; ni < 8; ++ni) {
        short8 b = *reinterpret_cast<const short8*>(
            WfB + (size_t)(w * 128 + ni * 16 + r) * 768 + k0 + q * 8);
        acc[ni] = __builtin_amdgcn_mfma_f32_16x16x32_bf16(a, b, acc[ni], 0, 0, 0);
      }
    }
#pragma unroll
    for (int ni = 0; ni < 8; ++ni) {
      float bv = bias0[w * 128 + ni * 16 + r];
#pragma unroll
      for (int rr = 0; rr < 4; ++rr)
        bufF[(q * 4 + rr) * 516 + w * 128 + ni * 16 + r] = fmaxf(acc[ni][rr] + bv, 0.0f);
    }
  }
  __syncthreads();
  // L1: h1 = relu(f * W1^T), N=256, K=512 (A from LDS bufF)
  layer_lds<256, 512, 0>(bufF, 516, W1B, b1, bufA, 260, w, r, q);
  __syncthreads();
  layer_lds<256, 256, 0>(bufA, 260, W2B, b2, bufB, 260, w, r, q);
  __syncthreads();
  layer_lds<128, 256, 0>(bufB, 260, W3B, b3, bufA, 132, w, r, q);
  __syncthreads();
  layer_lds<128, 128, 1>(bufA, 132, W4B, b4, bufB, 132, w, r, q);
  __syncthreads();

  // distances + act from LDS h4 (bufB) and ps — float4 vectorized
  for (int qq = t; qq < 960; qq += 256) {
    int p = qq >> 4;          // 0..59
    int pos = qq & 15;
    const float4* hv4 = reinterpret_cast<const float4*>(&bufB[pos * 132]);
    const float4* pv4 = reinterpret_cast<const float4*>(&ps[p * 132]);
    float s = 0.0f;
#pragma unroll 8
    for (int k = 0; k < 32; ++k) {
      float4 hv = hv4[k];
      float4 pv = pv4[k];
      float d0 = hv.x - pv.x, d1 = hv.y - pv.y, d2 = hv.z - pv.z, d3 = hv.w - pv.w;
      s = fmaf(d0, d0, s); s = fmaf(d1, d1, s); s = fmaf(d2, d2, s); s = fmaf(d3, d3, s);
    }
    float d = sqrtf(s);
    float a = __logf((d + 1.0f) / (d + EPSV));
    int gpos = pos0 + pos;
    int bimg = gpos / 196;
    int hw = gpos - bimg * 196;
    size_t idx = ((size_t)bimg * 60 + p) * 196 + hw;
    dist[idx] = d;
    act[idx] = a;
  }
}

// ---------------- top-5 smallest distances per (b,p): one WAVE per unit ----------------
__global__ void topk_kernel(const float* __restrict__ dist,
                            float* __restrict__ proto_act,
                            float* __restrict__ out_mind) {
  const int wid = threadIdx.x >> 6;
  const int lane = threadIdx.x & 63;
  const int u = blockIdx.x * 4 + wid;          // 0..959 exact (240 blocks)
  const float* rowp = dist + (size_t)u * 196;

  float v[4];
#pragma unroll
  for (int i = 0; i < 4; ++i) {
    int idx = lane + 64 * i;
    v[i] = (idx < 196) ? rowp[idx] : 1e30f;
  }

  float sd = 0.0f, sa = 0.0f;
#pragma unroll
  for (int round = 0; round < 5; ++round) {
    float lmin = fminf(fminf(v[0], v[1]), fminf(v[2], v[3]));
    float m = lmin;
#pragma unroll
    for (int off = 32; off >= 1; off >>= 1)
      m = fminf(m, __shfl_xor(m, off));
    unsigned long long msk = __ballot(lmin == m);
    int leader = __ffsll((long long)msk) - 1;
    if (lane == leader) {
      if (v[0] == m)      v[0] = 1e30f;
      else if (v[1] == m) v[1] = 1e30f;
      else if (v[2] == m) v[2] = 1e30f;
      else                v[3] = 1e30f;
    }
    sd += m;
    sa += __logf((m + 1.0f) / (m + EPSV));
  }
  if (lane == 0) {
    out_mind[u] = sd * 0.2f;
    proto_act[u] = sa * 0.2f;
  }
}

// ---------------- upsample 16x + logits tail block ----------------
__global__ void upsample_kernel(const float* __restrict__ act,
                                float* __restrict__ up,
                                const float* __restrict__ proto_act,
                                const float* __restrict__ lastW,
                                float* __restrict__ out_logits) {
  if (blockIdx.x < 47100) {
    int t = blockIdx.x * 256 + threadIdx.x;   // 12,057,600 exact
    int col4 = t % 56;
    int rem = t / 56;
    int y = rem % 224;
    int bp = rem / 224;
    float v = act[(size_t)bp * 196 + (y >> 4) * 14 + (col4 >> 2)];
    float4 val;
    val.x = v; val.y = v; val.z = v; val.w = v;
    reinterpret_cast<float4*>(up)[t] = val;
  } else {
    int t = threadIdx.x;
    if (t < 48) {
      int b = t / 3, c = t - b * 3;
      float s = 0.0f;
      for (int p = 0; p < 60; ++p)
        s += proto_act[b * 60 + p] * lastW[c * 60 + p];
      out_logits[t] = s;
    }
  }
}

extern "C" void kernel_launch(void* const* d_in, const int* in_sizes, int n_in,
                              void* d_out, int out_size, void* d_ws, size_t ws_size,
                              hipStream_t stream) {
  const float* x     = (const float*)d_in[0];
  const float* Wf    = (const float*)d_in[2];   // [512,768]
  const float* bf    = (const float*)d_in[3];
  const float* W1    = (const float*)d_in[4];   // [256,512]
  const float* b1    = (const float*)d_in[5];
  const float* W2    = (const float*)d_in[6];   // [256,256]
  const float* b2    = (const float*)d_in[7];
  const float* W3    = (const float*)d_in[8];   // [128,256]
  const float* b3    = (const float*)d_in[9];
  const float* W4    = (const float*)d_in[10];  // [128,128]
  const float* b4    = (const float*)d_in[11];
  const float* proto = (const float*)d_in[12];  // [60,128]
  const float* lastW = (const float*)d_in[13];  // [3,60]

  char* ws = (char*)d_ws;
  __hip_bfloat16* WfB = (__hip_bfloat16*)(ws + 0);         // 393216 elems
  __hip_bfloat16* W1B = (__hip_bfloat16*)(ws + 786432);    // 131072
  __hip_bfloat16* W2B = (__hip_bfloat16*)(ws + 1048576);   // 65536
  __hip_bfloat16* W3B = (__hip_bfloat16*)(ws + 1179648);   // 32768
  __hip_bfloat16* W4B = (__hip_bfloat16*)(ws + 1245184);   // 16384
  __hip_bfloat16* A0 = (__hip_bfloat16*)(ws + 1310720);    // [3136,768] bf16
  float* dist = (float*)(ws + 9339392);                    // [960,196] f32
  float* act  = (float*)(ws + 10092032);                   // [960,196] f32
  float* pact = (float*)(ws + 10844672);                   // [960] f32

  float* out        = (float*)d_out;
  float* out_logits = out;          // 48
  float* out_mind   = out + 48;     // 960
  float* out_up     = out + 1008;   // 48,230,400

  prep_kernel<<<1212, 256, 0, stream>>>((const float4*)Wf, (const float4*)W1,
                                        (const float4*)W2, (const float4*)W3,
                                        (const float4*)W4, (ushort4*)WfB, x, A0);
  mlp_dist_kernel<<<196, 256, 0, stream>>>(A0, WfB, bf, W1B, b1, W2B, b2,
                                           W3B, b3, W4B, b4, proto, dist, act);
  topk_kernel<<<240, 256, 0, stream>>>(dist, pact, out_mind);
  upsample_kernel<<<47101, 256, 0, stream>>>(act, out_up, pact, lastW, out_logits);
}

// Round 7
// 268.783 us; speedup vs baseline: 1.8029x; 1.0192x over previous
//
#include <hip/hip_runtime.h>
#include <hip/hip_bf16.h>

using short8  = __attribute__((ext_vector_type(8))) short;
using ushort8 = __attribute__((ext_vector_type(8))) unsigned short;
using floatx4 = __attribute__((ext_vector_type(4))) float;

#define EPSV 1e-4f

__device__ __forceinline__ unsigned short bfbits(float f) {
  __hip_bfloat16 h = __float2bfloat16(f);
  return *reinterpret_cast<unsigned short*>(&h);
}

// ---------------- prep: weight cvt f32 -> bf16 (contiguous dst) ----------------
__global__ void prep_kernel(const float4* __restrict__ Wf, const float4* __restrict__ W1,
                            const float4* __restrict__ W2, const float4* __restrict__ W3,
                            const float4* __restrict__ W4, ushort4* __restrict__ wdst) {
  int t = blockIdx.x * 256 + threadIdx.x;   // 159744 exact (624 blocks)
  const float4* src; int off;
  if (t < 98304)       { src = Wf; off = 0; }
  else if (t < 131072) { src = W1; off = 98304; }
  else if (t < 147456) { src = W2; off = 131072; }
  else if (t < 155648) { src = W3; off = 147456; }
  else                 { src = W4; off = 155648; }
  float4 v = src[t - off];
  ushort4 o;
  o.x = bfbits(v.x); o.y = bfbits(v.y); o.z = bfbits(v.z); o.w = bfbits(v.w);
  wdst[t] = o;
}

// ---------------- fused L0..L4 + distances + act ----------------
// LDS intermediates stored as bf16 (identical rounding to the old f32-store +
// convert-on-read path). h4 kept f32 for the distance computation.
template <int N, int K, int ACT, int OUTF32>
__device__ __forceinline__ void layer_lds(const unsigned short* __restrict__ A, int astride,
                                          const __hip_bfloat16* __restrict__ W,
                                          const float* __restrict__ bias,
                                          void* __restrict__ Cout, int cstride,
                                          int w, int r, int q) {
  constexpr int NA = N / 64;
  const int n0 = w * (N / 4);
  floatx4 acc[NA] = {};
#pragma unroll
  for (int k0 = 0; k0 < K; k0 += 32) {
    short8 a = *reinterpret_cast<const short8*>(A + r * astride + k0 + q * 8);
#pragma unroll
    for (int ni = 0; ni < NA; ++ni) {
      short8 b = *reinterpret_cast<const short8*>(W + (size_t)(n0 + ni * 16 + r) * K + k0 + q * 8);
      acc[ni] = __builtin_amdgcn_mfma_f32_16x16x32_bf16(a, b, acc[ni], 0, 0, 0);
    }
  }
#pragma unroll
  for (int ni = 0; ni < NA; ++ni) {
    float bv = bias[n0 + ni * 16 + r];
#pragma unroll
    for (int rr = 0; rr < 4; ++rr) {
      float v = acc[ni][rr] + bv;
      v = (ACT == 0) ? fmaxf(v, 0.0f) : 1.0f / (1.0f + __expf(-v));
      if (OUTF32)
        reinterpret_cast<float*>(Cout)[(q * 4 + rr) * cstride + n0 + ni * 16 + r] = v;
      else
        reinterpret_cast<unsigned short*>(Cout)[(q * 4 + rr) * cstride + n0 + ni * 16 + r] = bfbits(v);
    }
  }
}

__global__ __launch_bounds__(256) void mlp_dist_kernel(
    const float* __restrict__ x,
    const __hip_bfloat16* __restrict__ WfB, const float* __restrict__ bias0,
    const __hip_bfloat16* __restrict__ W1B, const float* __restrict__ b1,
    const __hip_bfloat16* __restrict__ W2B, const float* __restrict__ b2,
    const __hip_bfloat16* __restrict__ W3B, const float* __restrict__ b3,
    const __hip_bfloat16* __restrict__ W4B, const float* __restrict__ b4,
    const float* __restrict__ proto,
    float* __restrict__ dist, float* __restrict__ act,
    float* __restrict__ out_logits) {
  __shared__ unsigned short bufF[16 * 520];   // f  (bf16), stride 520
  __shared__ unsigned short bufA[16 * 264];   // h1 / h3 (bf16)
  __shared__ unsigned short bufB[16 * 264];   // h2 (bf16)
  __shared__ float          h4f[16 * 132];    // h4 (f32, for distances)
  __shared__ float          ps[60 * 132];     // prototypes f32, stride 132
  const int t = threadIdx.x;
  const int w = t >> 6;
  const int lane = t & 63;
  const int r = lane & 15;
  const int q = lane >> 4;
  const int pos0 = blockIdx.x * 16;    // 196 blocks

  // zero logits for the atomic accumulation in the final launch
  if (blockIdx.x == 0 && t < 48) out_logits[t] = 0.0f;

  // stage prototypes (f32, padded stride 132)
  {
    const float4* p4 = reinterpret_cast<const float4*>(proto);
    for (int i = t; i < 1920; i += 256) {
      int p = i >> 5, kc = i & 31;
      *reinterpret_cast<float4*>(&ps[p * 132 + kc * 4]) = p4[i];
    }
  }

  // L0: f = relu(patch(x) * Wf^T + bf); A-frag loaded DIRECTLY from x.
  // row r -> pos = pos0+r; col k = k0+q*8 -> (c,kh,kw0): 8 contiguous floats.
  {
    int pos = pos0 + r;
    int b = pos / 196;
    int ij = pos - b * 196;
    int i = ij / 14;
    int j = ij - i * 14;
    const float* xb = x + (size_t)b * 150528 + (i * 16) * 224 + j * 16;
    floatx4 acc[8] = {};
#pragma unroll 4
    for (int k0 = 0; k0 < 768; k0 += 32) {
      int k = k0 + q * 8;
      int c = k >> 8;
      int kh = (k >> 4) & 15;
      int kw0 = k & 15;              // 0 or 8
      const float* ap = xb + c * 50176 + kh * 224 + kw0;
      float4 lo = *reinterpret_cast<const float4*>(ap);
      float4 hi = *reinterpret_cast<const float4*>(ap + 4);
      short8 a;
      a[0] = bfbits(lo.x); a[1] = bfbits(lo.y); a[2] = bfbits(lo.z); a[3] = bfbits(lo.w);
      a[4] = bfbits(hi.x); a[5] = bfbits(hi.y); a[6] = bfbits(hi.z); a[7] = bfbits(hi.w);
#pragma unroll
      for (int ni = 0; ni < 8; ++ni) {
        short8 bfr = *reinterpret_cast<const short8*>(
            WfB + (size_t)(w * 128 + ni * 16 + r) * 768 + k0 + q * 8);
        acc[ni] = __builtin_amdgcn_mfma_f32_16x16x32_bf16(a, bfr, acc[ni], 0, 0, 0);
      }
    }
#pragma unroll
    for (int ni = 0; ni < 8; ++ni) {
      float bv = bias0[w * 128 + ni * 16 + r];
#pragma unroll
      for (int rr = 0; rr < 4; ++rr)
        bufF[(q * 4 + rr) * 520 + w * 128 + ni * 16 + r] = bfbits(fmaxf(acc[ni][rr] + bv, 0.0f));
    }
  }
  __syncthreads();
  layer_lds<256, 512, 0, 0>(bufF, 520, W1B, b1, bufA, 264, w, r, q);
  __syncthreads();
  layer_lds<256, 256, 0, 0>(bufA, 264, W2B, b2, bufB, 264, w, r, q);
  __syncthreads();
  layer_lds<128, 256, 0, 0>(bufB, 264, W3B, b3, bufA, 264, w, r, q);
  __syncthreads();
  layer_lds<128, 128, 1, 1>(bufA, 264, W4B, b4, h4f, 132, w, r, q);
  __syncthreads();

  // distances + act from LDS h4 (f32) and ps — float4 vectorized
  for (int qq = t; qq < 960; qq += 256) {
    int p = qq >> 4;          // 0..59
    int pos = qq & 15;
    const float4* hv4 = reinterpret_cast<const float4*>(&h4f[pos * 132]);
    const float4* pv4 = reinterpret_cast<const float4*>(&ps[p * 132]);
    float s = 0.0f;
#pragma unroll 8
    for (int k = 0; k < 32; ++k) {
      float4 hv = hv4[k];
      float4 pv = pv4[k];
      float d0 = hv.x - pv.x, d1 = hv.y - pv.y, d2 = hv.z - pv.z, d3 = hv.w - pv.w;
      s = fmaf(d0, d0, s); s = fmaf(d1, d1, s); s = fmaf(d2, d2, s); s = fmaf(d3, d3, s);
    }
    float d = sqrtf(s);
    float a = __logf((d + 1.0f) / (d + EPSV));
    int gpos = pos0 + pos;
    int bimg = gpos / 196;
    int hw = gpos - bimg * 196;
    size_t idx = ((size_t)bimg * 60 + p) * 196 + hw;
    dist[idx] = d;
    act[idx] = a;
  }
}

// ---------------- final: upsample (blocks 0..47099) + topk/logits (tail 240 blocks) ----------------
__global__ void final_kernel(const float* __restrict__ act,
                             float* __restrict__ up,
                             const float* __restrict__ dist,
                             const float* __restrict__ lastW,
                             float* __restrict__ out_logits,
                             float* __restrict__ out_mind) {
  if (blockIdx.x < 47100) {
    int t = blockIdx.x * 256 + threadIdx.x;   // 12,057,600 exact
    int col4 = t % 56;
    int rem = t / 56;
    int y = rem % 224;
    int bp = rem / 224;
    float v = act[(size_t)bp * 196 + (y >> 4) * 14 + (col4 >> 2)];
    float4 val;
    val.x = v; val.y = v; val.z = v; val.w = v;
    reinterpret_cast<float4*>(up)[t] = val;
  } else {
    // top-5 smallest distances per (b,p): one wave per unit.
    // act = log((d+1)/(d+eps)) is strictly decreasing in d.
    const int wid = threadIdx.x >> 6;
    const int lane = threadIdx.x & 63;
    const int u = (blockIdx.x - 47100) * 4 + wid;   // 0..959 exact
    const float* rowp = dist + (size_t)u * 196;

    float v[4];
#pragma unroll
    for (int i = 0; i < 4; ++i) {
      int idx = lane + 64 * i;
      v[i] = (idx < 196) ? rowp[idx] : 1e30f;
    }

    float sd = 0.0f, sa = 0.0f;
#pragma unroll
    for (int round = 0; round < 5; ++round) {
      float lmin = fminf(fminf(v[0], v[1]), fminf(v[2], v[3]));
      float m = lmin;
#pragma unroll
      for (int off = 32; off >= 1; off >>= 1)
        m = fminf(m, __shfl_xor(m, off));
      unsigned long long msk = __ballot(lmin == m);
      int leader = __ffsll((long long)msk) - 1;
      if (lane == leader) {
        if (v[0] == m)      v[0] = 1e30f;
        else if (v[1] == m) v[1] = 1e30f;
        else if (v[2] == m) v[2] = 1e30f;
        else                v[3] = 1e30f;
      }
      sd += m;
      sa += __logf((m + 1.0f) / (m + EPSV));
    }
    int b = u / 60, p = u - b * 60;
    float pa = sa * 0.2f;
    if (lane == 0) out_mind[u] = sd * 0.2f;
    if (lane < 3) atomicAdd(&out_logits[b * 3 + lane], pa * lastW[lane * 60 + p]);
  }
}

extern "C" void kernel_launch(void* const* d_in, const int* in_sizes, int n_in,
                              void* d_out, int out_size, void* d_ws, size_t ws_size,
                              hipStream_t stream) {
  const float* x     = (const float*)d_in[0];
  const float* Wf    = (const float*)d_in[2];   // [512,768]
  const float* bf    = (const float*)d_in[3];
  const float* W1    = (const float*)d_in[4];   // [256,512]
  const float* b1    = (const float*)d_in[5];
  const float* W2    = (const float*)d_in[6];   // [256,256]
  const float* b2    = (const float*)d_in[7];
  const float* W3    = (const float*)d_in[8];   // [128,256]
  const float* b3    = (const float*)d_in[9];
  const float* W4    = (const float*)d_in[10];  // [128,128]
  const float* b4    = (const float*)d_in[11];
  const float* proto = (const float*)d_in[12];  // [60,128]
  const float* lastW = (const float*)d_in[13];  // [3,60]

  char* ws = (char*)d_ws;
  __hip_bfloat16* WfB = (__hip_bfloat16*)(ws + 0);         // 393216 elems
  __hip_bfloat16* W1B = (__hip_bfloat16*)(ws + 786432);    // 131072
  __hip_bfloat16* W2B = (__hip_bfloat16*)(ws + 1048576);   // 65536
  __hip_bfloat16* W3B = (__hip_bfloat16*)(ws + 1179648);   // 32768
  __hip_bfloat16* W4B = (__hip_bfloat16*)(ws + 1245184);   // 16384
  float* dist = (float*)(ws + 1310720);                    // [960,196] f32
  float* act  = (float*)(ws + 2063360);                    // [960,196] f32

  float* out        = (float*)d_out;
  float* out_logits = out;          // 48
  float* out_mind   = out + 48;     // 960
  float* out_up     = out + 1008;   // 48,230,400

  prep_kernel<<<624, 256, 0, stream>>>((const float4*)Wf, (const float4*)W1,
                                       (const float4*)W2, (const float4*)W3,
                                       (const float4*)W4, (ushort4*)WfB);
  mlp_dist_kernel<<<196, 256, 0, stream>>>(x, WfB, bf, W1B, b1, W2B, b2,
                                           W3B, b3, W4B, b4, proto, dist, act,
                                           out_logits);
  final_kernel<<<47340, 256, 0, stream>>>(act, out_up, dist, lastW,
                                          out_logits, out_mind);
}